// Round 9
// baseline (116.849 us; speedup 1.0000x reference)
//
#include <hip/hip_runtime.h>
#include <hip/hip_fp16.h>

// Problem constants
#define Wd    96
#define Hd    96
#define HW    9216           // 96*96
#define Bn    4
#define Cn    64             // channels per section
#define C3    192            // 3*Cn
#define On    64             // out channels
#define NPIX  (Bn*HW)        // 36864
#define NFEAT (Bn*Cn*HW)     // 2359296 elements per output tensor
#define NWTB  (9*6*4*512)    // 110592 f16 frag-linear deform weights
#define NWTB2 (18*2*64*8)    // 18432 f16 frag-linear offset weights
#define NRB3  (Bn*(HW/32))   // 1152 repack blocks (32-px strips)

// Halo geometry: 16x2 px tile -> rows yb-2..yb+3, cols xb-3..xb+17
// Layout: linear slots [pr(126)][slot(24)] *16B, NO pad; slot = chblk ^ (pr&7)
#define HR2   6
#define HC    21
#define NPR2  (HR2*HC)       // 126 staged pixel rows
#define SELEM (NPR2*24)      // 3024 f4v staging elements
#define HALO16 3072          // f4v slots incl. tail pad for async DMA overrun
#define HALO_B (HALO16*16)   // 49152
#define NFBLK 1152           // fused blocks (6 x 48 x 4)

typedef __attribute__((ext_vector_type(8))) short s8v;       // 8 f16 (raw bits)
typedef __attribute__((ext_vector_type(8))) _Float16 h8v;    // 8 f16 (MFMA operand)
typedef __attribute__((ext_vector_type(4))) unsigned int u4v;
typedef __attribute__((ext_vector_type(4))) float f4v;       // MFMA accum / float4

__device__ __forceinline__ unsigned packh(float lo, float hi) {
    __half2 h = __floats2half2_rn(lo, hi);
    return __builtin_bit_cast(unsigned, h);
}

__device__ __forceinline__ void gload_lds16(const void* g, void* l) {
    __builtin_amdgcn_global_load_lds(
        (const __attribute__((address_space(1))) unsigned int*)g,
        (__attribute__((address_space(3))) unsigned int*)l, 16, 0, 0);
}

// ===========================================================================
// repack_wts: unchanged from R8. blocks [0, NRB3): NCHW -> f16 NHWC packed +
// fused diff. blocks [NRB3, ...): weight repacks.
// ===========================================================================
__global__ __launch_bounds__(256) void repack_wts_kernel(
        const float* __restrict__ ref,
        const float* __restrict__ dist,
        unsigned int* __restrict__ packed,    // [NPIX][96] f16-pairs
        float* __restrict__ out_diff,
        const float* __restrict__ dw,
        const float* __restrict__ ow,
        __half* __restrict__ wtb,
        __half* __restrict__ wtb2) {
    __shared__ unsigned lds[96][33];          // 12672 B, odd stride

    int tid = threadIdx.x;

    if (blockIdx.x >= NRB3) {
        int e = (int)(blockIdx.x - NRB3) * 256 + tid;
        if (e < NWTB) {
            int j = e & 7;
            int L = (e >> 3) & 63;
            int mt = (e >> 9) & 3;
            int rest = e >> 11;
            int kc = rest % 6;
            int tap = rest / 6;
            int o = mt * 16 + (L & 15);
            int c = kc * 32 + (L >> 4) * 8 + j;
            wtb[e] = __float2half(dw[((size_t)o * C3 + c) * 9 + tap]);
        } else if (e < NWTB + NWTB2) {
            int e2 = e - NWTB;
            int j = e2 & 7;
            int L = (e2 >> 3) & 63;
            int mt = (e2 >> 9) & 1;
            int kc2 = e2 >> 10;           // 0..17 = t*2+kc
            int v = mt * 16 + (L & 15);
            int k = kc2 * 32 + ((L >> 4) & 3) * 8 + j;
            int c = k & 63;
            int tap = k >> 6;
            float val = (v < 18) ? ow[((size_t)v * Cn + c) * 9 + tap] : 0.f;
            wtb2[e2] = __float2half(val);
        }
        return;
    }

    // ---- repack part: 32-px strip ----
    int blk = blockIdx.x;
    int b = blk / (HW / 32);
    int pb = (blk - b * (HW / 32)) * 32;
    int pxg = tid & 7;                        // 8 px-quads of 4
    int chp = tid >> 3;                       // channel pair 0..31

    size_t base0 = ((size_t)(b * Cn + 2 * chp)) * HW + pb + pxg * 4;
    size_t base1 = base0 + HW;

    f4v r0 = *(const f4v*)(ref + base0);
    f4v r1 = *(const f4v*)(ref + base1);
    f4v d0 = *(const f4v*)(dist + base0);
    f4v d1 = *(const f4v*)(dist + base1);

    f4v q0 = (r0 - d0) * (r0 - d0);
    f4v q1 = (r1 - d1) * (r1 - d1);
    *(f4v*)(out_diff + base0) = q0;
    *(f4v*)(out_diff + base1) = q1;

#pragma unroll
    for (int j = 0; j < 4; ++j) {
        int p = pxg * 4 + j;
        lds[chp][p]      = packh(r0[j], r1[j]);
        lds[32 + chp][p] = packh(d0[j], d1[j]);
        lds[64 + chp][p] = packh(q0[j], q1[j]);
    }
    __syncthreads();

    // vectorized transpose-out: thread owns (px, 12-ch-pair slab)
    {
        int p = tid >> 3;                     // 0..31
        int part = tid & 7;                   // 0..7
        unsigned* pko = packed + ((size_t)(b * HW + pb) + p) * 96 + part * 12;
#pragma unroll
        for (int q = 0; q < 3; ++q) {
            u4v w;
#pragma unroll
            for (int j = 0; j < 4; ++j)
                w[j] = lds[part * 12 + q * 4 + j][p];
            *(u4v*)(pko + q * 4) = w;
        }
    }
}

// ===========================================================================
// fused_mfma: 16x2 px tile, 384 thr = 2 row-groups x 3-way split-K (Phase B).
// Halo staged via async global_load_lds (dest linear in tid, per-lane global
// src), layout [pr][slot]*16B with slot = chblk ^ (pr&7) XOR swizzle:
// pitch 384 (no pad) is bank-uniform under the swizzle for ALL reads.
// LDS 51456 B -> 3 blocks/CU. Phase-B reduction aliases halo.
// ===========================================================================
struct Ctx {
    int o00, o01, o10, o11;      // global byte offsets (fallback path)
    int l00, l01, l10, l11;      // pr*384 + (pr&7) packed (fast path)
    float W00, W01, W10, W11;
    int inh;                     // all 4 corners inside staged halo
};

__device__ __forceinline__ Ctx mkctx(int t, int y, int x, int xb, int yb,
                                     float2 o2) {
    Ctx c;
    float py = (float)(y - 1 + t / 3) + o2.x;
    float pxs = (float)(x - 1 + t % 3) + o2.y;
    float fy = floorf(py), fx = floorf(pxs);
    int y0 = (int)fy, x0 = (int)fx;
    int y1 = y0 + 1, x1 = x0 + 1;
    float ay = py - fy, ax = pxs - fx;
    bool vy0 = (unsigned)y0 < (unsigned)Hd;
    bool vy1 = (unsigned)y1 < (unsigned)Hd;
    bool vx0 = (unsigned)x0 < (unsigned)Wd;
    bool vx1 = (unsigned)x1 < (unsigned)Wd;
    c.W00 = (vy0 && vx0) ? (1.f - ay) * (1.f - ax) : 0.f;
    c.W01 = (vy0 && vx1) ? (1.f - ay) * ax : 0.f;
    c.W10 = (vy1 && vx0) ? ay * (1.f - ax) : 0.f;
    c.W11 = (vy1 && vx1) ? ay * ax : 0.f;
    int y0c = min(max(y0, 0), Hd - 1), y1c = min(max(y1, 0), Hd - 1);
    int x0c = min(max(x0, 0), Wd - 1), x1c = min(max(x1, 0), Wd - 1);
    c.o00 = (y0c * Wd + x0c) * (C3 * 2);
    c.o01 = (y0c * Wd + x1c) * (C3 * 2);
    c.o10 = (y1c * Wd + x0c) * (C3 * 2);
    c.o11 = (y1c * Wd + x1c) * (C3 * 2);
    int iy0 = y0c - yb + 2, iy1 = y1c - yb + 2;      // halo row 0 = yb-2
    int ix0 = x0c - xb + 3, ix1 = x1c - xb + 3;
    c.inh = ((unsigned)iy0 < (unsigned)HR2) & ((unsigned)iy1 < (unsigned)HR2) &
            ((unsigned)ix0 < (unsigned)HC) & ((unsigned)ix1 < (unsigned)HC);
    int p00 = iy0 * HC + ix0, p01 = iy0 * HC + ix1;
    int p10 = iy1 * HC + ix0, p11 = iy1 * HC + ix1;
    c.l00 = p00 * 384 + (p00 & 7);
    c.l01 = p01 * 384 + (p01 & 7);
    c.l10 = p10 * 384 + (p10 & 7);
    c.l11 = p11 * 384 + (p11 & 7);
    return c;
}

__device__ __forceinline__ __half2 uh2(unsigned u) {
    return __builtin_bit_cast(__half2, u);
}

// Bilinear blend on packed f16 pairs + 4 MFMAs, for one (tap, kc-triple).
// rw already gathered by caller.
__device__ __forceinline__ void bilin_mfma(const s8v* rw, const Ctx& cc,
        const s8v* __restrict__ Ap, int t, int kb, int L, f4v* acc) {
    __half2 w00 = __float2half2_rn(cc.W00);
    __half2 w01 = __float2half2_rn(cc.W01);
    __half2 w10 = __float2half2_rn(cc.W10);
    __half2 w11 = __float2half2_rn(cc.W11);
#pragma unroll
    for (int i = 0; i < 3; ++i) {
        int kc = kb + i;
        u4v u00 = __builtin_bit_cast(u4v, rw[0 * 3 + i]);
        u4v u01 = __builtin_bit_cast(u4v, rw[1 * 3 + i]);
        u4v u10 = __builtin_bit_cast(u4v, rw[2 * 3 + i]);
        u4v u11 = __builtin_bit_cast(u4v, rw[3 * 3 + i]);
        u4v bu;
#pragma unroll
        for (int p = 0; p < 4; ++p) {
            __half2 v = __hmul2(uh2(u00[p]), w00);
            v = __hfma2(uh2(u01[p]), w01, v);
            v = __hfma2(uh2(u10[p]), w10, v);
            v = __hfma2(uh2(u11[p]), w11, v);
            bu[p] = __builtin_bit_cast(unsigned, v);
        }
        h8v bfrag = __builtin_bit_cast(h8v, bu);
#pragma unroll
        for (int mt = 0; mt < 4; ++mt) {
            h8v a = __builtin_bit_cast(h8v, Ap[((t * 6 + kc) * 4 + mt) * 64 + L]);
            acc[mt] = __builtin_amdgcn_mfma_f32_16x16x32_f16(a, bfrag, acc[mt], 0, 0, 0);
        }
    }
}

__global__ __launch_bounds__(384, 4) void fused_mfma(
        const __half* __restrict__ packed,
        const __half* __restrict__ wtb2,
        const float* __restrict__ ob,
        const __half* __restrict__ wtb,
        const float* __restrict__ db,
        float* __restrict__ out) {
    __shared__ __align__(16) char smem[HALO_B + 2 * 16 * 18 * 4];   // 51456 B
    float (*off_l)[18] = (float(*)[18])(smem + HALO_B);   // [32][18], 2304 B
    float* redB = (float*)smem;                           // aliases halo

    int tid = threadIdx.x;
    int L = tid & 63;
    int wv = tid >> 6;                        // 0..5
    int g  = wv / 3;                          // row group 0..1
    int kv = wv - g * 3;                      // split-K 0..2 (Phase B)
    int px = L & 15;
    int lg = L >> 4;
    int blk = blockIdx.x;
    int region = (blk & 7) * 144 + (blk >> 3);        // 1152 blocks, XCD swizzle
    int b = region / 288;
    int rt = region - b * 288;
    int yt = rt / 6;
    int xt = rt - yt * 6;
    int yb = yt * 2, xb = xt * 16;            // tile: rows yb..yb+1, cols xb..+15
    int y = yb + g, x = xb + px;
    int pb = y * Wd + xb;                     // this group's output row base
    int tbase = kv * 3;

    const char* pkb = (const char*)packed + (size_t)b * HW * (C3 * 2);
    const char* hb = (const char*)smem;

    // ------- stage halo: async DMA, dest linear in tid, swizzled source ----
#pragma unroll
    for (int s = 0; s < 8; ++s) {
        int gi = tid + s * 384;               // dest slot (linear, incl. pad)
        int giS = min(gi, SELEM - 1);         // source clamped to valid range
        int pr = giS / 24;
        int slot = giS - pr * 24;
        int chblk = slot ^ (pr & 7);          // inverse swizzle on source
        int iy = pr / HC, ix = pr - iy * HC;
        int gy = min(max(yb - 2 + iy, 0), Hd - 1);
        int gx = min(max(xb - 3 + ix, 0), Wd - 1);
        gload_lds16(pkb + ((size_t)(gy * Wd + gx)) * 384 + chblk * 16,
                    (char*)smem + (size_t)gi * 16);
    }
    __syncthreads();

    // ------- Phase A: offset conv — ONE wave per row-group, all 9 taps -----
    if (kv == 0) {
        const s8v* Ap = (const s8v*)wtb2;
        f4v acc0 = {0.f, 0.f, 0.f, 0.f};
        f4v acc1 = {0.f, 0.f, 0.f, 0.f};
#pragma unroll
        for (int t = 0; t < 9; ++t) {
            int ty = t / 3, tx = t - ty * 3;
            int yy = y - 1 + ty, xx = x - 1 + tx;
            bool val = (unsigned)yy < (unsigned)Hd && (unsigned)xx < (unsigned)Wd;
            short m = val ? (short)-1 : (short)0;
            int pr = (g + 1 + ty) * HC + (px + 2 + tx);
            int pbase = pr * 384;
            int key = pr & 7;
#pragma unroll
            for (int kc = 0; kc < 2; ++kc) {
                int chblk = kc * 4 + lg;
                s8v braw = *(const s8v*)(hb + pbase + ((chblk ^ key) << 4)) & m;
                h8v bfrag = __builtin_bit_cast(h8v, braw);
                h8v a0 = __builtin_bit_cast(h8v, Ap[((t * 2 + kc) * 2 + 0) * 64 + L]);
                h8v a1 = __builtin_bit_cast(h8v, Ap[((t * 2 + kc) * 2 + 1) * 64 + L]);
                acc0 = __builtin_amdgcn_mfma_f32_16x16x32_f16(a0, bfrag, acc0, 0, 0, 0);
                acc1 = __builtin_amdgcn_mfma_f32_16x16x32_f16(a1, bfrag, acc1, 0, 0, 0);
            }
        }
#pragma unroll
        for (int r = 0; r < 4; ++r) {
            int v = lg * 4 + r;
            off_l[g * 16 + px][v] = acc0[r] + ob[v];
        }
        if (lg == 0) {
#pragma unroll
            for (int r = 0; r < 2; ++r)
                off_l[g * 16 + px][16 + r] = acc1[r] + ob[16 + r];
        }
    }
    __syncthreads();

    // ---------------- Phase B: deform conv ----------------
    const s8v* Ap = (const s8v*)wtb;

    Ctx ctx[3];
    int ok = 1;
#pragma unroll
    for (int tt = 0; tt < 3; ++tt) {
        int t = tbase + tt;
        float2 o2 = {off_l[g * 16 + px][2 * t], off_l[g * 16 + px][2 * t + 1]};
        ctx[tt] = mkctx(t, y, x, xb, yb, o2);
        ok &= ctx[tt].inh;
    }

    f4v acc[4];
    acc[0] = acc[1] = acc[2] = acc[3] = (f4v){0.f, 0.f, 0.f, 0.f};

    if (__all(ok)) {
        // fast path: bilinear gathers from swizzled LDS halo
#pragma unroll
        for (int h = 0; h < 6; ++h) {             // 3 taps x 2 halves
            int tt = h >> 1;
            int t = tbase + tt;
            int kb = (h & 1) * 3;
            const Ctx cc = ctx[tt];
            int b00 = cc.l00 & ~127, k00 = cc.l00 & 7;
            int b01 = cc.l01 & ~127, k01 = cc.l01 & 7;
            int b10 = cc.l10 & ~127, k10 = cc.l10 & 7;
            int b11 = cc.l11 & ~127, k11 = cc.l11 & 7;
            s8v rw[12];
#pragma unroll
            for (int i = 0; i < 3; ++i) {
                int cb = (kb + i) * 4 + lg;
                rw[0 * 3 + i] = *(const s8v*)(hb + b00 + ((cb ^ k00) << 4));
                rw[1 * 3 + i] = *(const s8v*)(hb + b01 + ((cb ^ k01) << 4));
                rw[2 * 3 + i] = *(const s8v*)(hb + b10 + ((cb ^ k10) << 4));
                rw[3 * 3 + i] = *(const s8v*)(hb + b11 + ((cb ^ k11) << 4));
            }
            bilin_mfma(rw, cc, Ap, t, kb, L, acc);
        }
    } else {
        // fallback: global gathers (rare; arbitrary offsets stay correct)
#pragma unroll
        for (int h = 0; h < 6; ++h) {
            int tt = h >> 1;
            int t = tbase + tt;
            int kb = (h & 1) * 3;
            const Ctx cc = ctx[tt];
            s8v rw[12];
#pragma unroll
            for (int i = 0; i < 3; ++i) {
                int co = ((kb + i) * 4 + lg) * 16;
                rw[0 * 3 + i] = *(const s8v*)(pkb + cc.o00 + co);
                rw[1 * 3 + i] = *(const s8v*)(pkb + cc.o01 + co);
                rw[2 * 3 + i] = *(const s8v*)(pkb + cc.o10 + co);
                rw[3 * 3 + i] = *(const s8v*)(pkb + cc.o11 + co);
            }
            bilin_mfma(rw, cc, Ap, t, kb, L, acc);
        }
    }

    // -------- reduction: redB aliases halo (all halo reads done) -----------
    __syncthreads();
    if (kv != 0) {
        float* r = redB + ((g * 2 + kv - 1) * 64 + L) * 17;
#pragma unroll
        for (int mt = 0; mt < 4; ++mt)
#pragma unroll
            for (int q = 0; q < 4; ++q)
                r[mt * 4 + q] = acc[mt][q];
    }
    __syncthreads();
    if (kv == 0) {
        const float* r0 = redB + ((g * 2 + 0) * 64 + L) * 17;
        const float* r1 = redB + ((g * 2 + 1) * 64 + L) * 17;
#pragma unroll
        for (int mt = 0; mt < 4; ++mt) {
#pragma unroll
            for (int q = 0; q < 4; ++q) {
                int o = mt * 16 + lg * 4 + q;
                float v = acc[mt][q] + r0[mt * 4 + q] + r1[mt * 4 + q] + db[o];
                out[((size_t)(b * On + o)) * HW + pb + px] = fmaxf(v, 0.f);
            }
        }
    }
}

// ---------------------------------------------------------------------------
extern "C" void kernel_launch(void* const* d_in, const int* in_sizes, int n_in,
                              void* d_out, int out_size, void* d_ws, size_t ws_size,
                              hipStream_t stream) {
    const float* ref  = (const float*)d_in[0];
    const float* dist = (const float*)d_in[1];
    const float* ow   = (const float*)d_in[2];
    const float* ob   = (const float*)d_in[3];
    const float* dw   = (const float*)d_in[4];
    const float* db   = (const float*)d_in[5];

    float* out = (float*)d_out;               // [feat | diff], each NFEAT f32

    // ws: wtb f16 | wtb2 f16 | packed f16 [NPIX][192]
    __half* ws_wtb  = (__half*)d_ws;
    __half* ws_wtb2 = ws_wtb + NWTB;
    __half* ws_pk   = ws_wtb2 + NWTB2;

    int wts_blocks = (NWTB + NWTB2 + 255) / 256;      // 504
    repack_wts_kernel<<<NRB3 + wts_blocks, 256, 0, stream>>>(
        ref, dist, (unsigned int*)ws_pk, out + NFEAT, dw, ow, ws_wtb, ws_wtb2);
    fused_mfma<<<NFBLK, 384, 0, stream>>>(
        ws_pk, ws_wtb2, ob, ws_wtb, db, out);
}

// Round 11
// 115.438 us; speedup vs baseline: 1.0122x; 1.0122x over previous
//
#include <hip/hip_runtime.h>
#include <hip/hip_fp16.h>

// Problem constants
#define Wd    96
#define Hd    96
#define HW    9216           // 96*96
#define Bn    4
#define Cn    64             // channels per section
#define C3    192            // 3*Cn
#define On    64             // out channels
#define NPIX  (Bn*HW)        // 36864
#define NFEAT (Bn*Cn*HW)     // 2359296 elements per output tensor
#define NWTB  (9*6*4*512)    // 110592 f16 frag-linear deform weights
#define NWTB2 (18*2*64*8)    // 18432 f16 frag-linear offset weights
#define NRB3  (Bn*(HW/32))   // 1152 repack blocks (32-px strips)

// Halo geometry: 16x2 px tile -> rows yb-2..yb+3, cols xb-3..xb+17
// SECTION-MAJOR layout: [sec(3)][pr(126)][slot(8)]*16B, slot = chb3 ^ (pr&7)
// sec 0 = ref (chblk 0-7), sec 1 = dist (8-15), sec 2 = diff (16-23)
#define HR2   6
#define HC    21
#define NPR2  (HR2*HC)       // 126 staged pixel rows
#define SECT_SL 1008         // slots per section (126*8)
#define SECT_B  16128        // bytes per section (1008*16)
#define SELEM   3024         // total valid f4v slots
#define HALO16  3072         // slots incl. 48-slot tail pad for DMA overrun
#define HALO_B  (HALO16*16)  // 49152 (off_l lives AFTER this)
#define NFBLK 1152           // fused blocks (6 x 48 x 4)

typedef __attribute__((ext_vector_type(8))) short s8v;       // 8 f16 (raw bits)
typedef __attribute__((ext_vector_type(8))) _Float16 h8v;    // 8 f16 (MFMA operand)
typedef __attribute__((ext_vector_type(4))) unsigned int u4v;
typedef __attribute__((ext_vector_type(4))) float f4v;       // MFMA accum / float4

__device__ __forceinline__ unsigned packh(float lo, float hi) {
    __half2 h = __floats2half2_rn(lo, hi);
    return __builtin_bit_cast(unsigned, h);
}

__device__ __forceinline__ void gload_lds16(const void* g, void* l) {
    __builtin_amdgcn_global_load_lds(
        (const __attribute__((address_space(1))) unsigned int*)g,
        (__attribute__((address_space(3))) unsigned int*)l, 16, 0, 0);
}

// ===========================================================================
// repack_wts: unchanged (proven). blocks [0, NRB3): NCHW -> f16 NHWC packed +
// fused diff. blocks [NRB3, ...): weight repacks.
// ===========================================================================
__global__ __launch_bounds__(256) void repack_wts_kernel(
        const float* __restrict__ ref,
        const float* __restrict__ dist,
        unsigned int* __restrict__ packed,    // [NPIX][96] f16-pairs
        float* __restrict__ out_diff,
        const float* __restrict__ dw,
        const float* __restrict__ ow,
        __half* __restrict__ wtb,
        __half* __restrict__ wtb2) {
    __shared__ unsigned lds[96][33];          // 12672 B, odd stride

    int tid = threadIdx.x;

    if (blockIdx.x >= NRB3) {
        int e = (int)(blockIdx.x - NRB3) * 256 + tid;
        if (e < NWTB) {
            int j = e & 7;
            int L = (e >> 3) & 63;
            int mt = (e >> 9) & 3;
            int rest = e >> 11;
            int kc = rest % 6;
            int tap = rest / 6;
            int o = mt * 16 + (L & 15);
            int c = kc * 32 + (L >> 4) * 8 + j;
            wtb[e] = __float2half(dw[((size_t)o * C3 + c) * 9 + tap]);
        } else if (e < NWTB + NWTB2) {
            int e2 = e - NWTB;
            int j = e2 & 7;
            int L = (e2 >> 3) & 63;
            int mt = (e2 >> 9) & 1;
            int kc2 = e2 >> 10;           // 0..17 = t*2+kc
            int v = mt * 16 + (L & 15);
            int k = kc2 * 32 + ((L >> 4) & 3) * 8 + j;
            int c = k & 63;
            int tap = k >> 6;
            float val = (v < 18) ? ow[((size_t)v * Cn + c) * 9 + tap] : 0.f;
            wtb2[e2] = __float2half(val);
        }
        return;
    }

    // ---- repack part: 32-px strip ----
    int blk = blockIdx.x;
    int b = blk / (HW / 32);
    int pb = (blk - b * (HW / 32)) * 32;
    int pxg = tid & 7;                        // 8 px-quads of 4
    int chp = tid >> 3;                       // channel pair 0..31

    size_t base0 = ((size_t)(b * Cn + 2 * chp)) * HW + pb + pxg * 4;
    size_t base1 = base0 + HW;

    f4v r0 = *(const f4v*)(ref + base0);
    f4v r1 = *(const f4v*)(ref + base1);
    f4v d0 = *(const f4v*)(dist + base0);
    f4v d1 = *(const f4v*)(dist + base1);

    f4v q0 = (r0 - d0) * (r0 - d0);
    f4v q1 = (r1 - d1) * (r1 - d1);
    *(f4v*)(out_diff + base0) = q0;
    *(f4v*)(out_diff + base1) = q1;

#pragma unroll
    for (int j = 0; j < 4; ++j) {
        int p = pxg * 4 + j;
        lds[chp][p]      = packh(r0[j], r1[j]);
        lds[32 + chp][p] = packh(d0[j], d1[j]);
        lds[64 + chp][p] = packh(q0[j], q1[j]);
    }
    __syncthreads();

    // vectorized transpose-out: thread owns (px, 12-ch-pair slab)
    {
        int p = tid >> 3;                     // 0..31
        int part = tid & 7;                   // 0..7
        unsigned* pko = packed + ((size_t)(b * HW + pb) + p) * 96 + part * 12;
#pragma unroll
        for (int q = 0; q < 3; ++q) {
            u4v w;
#pragma unroll
            for (int j = 0; j < 4; ++j)
                w[j] = lds[part * 12 + q * 4 + j][p];
            *(u4v*)(pko + q * 4) = w;
        }
    }
}

// ===========================================================================
// fused_mfma: 16x2 px tile, 384 thr = 2 row-groups x 3-way split-K (Phase B).
// Section-major swizzled halo; batch-split async DMA with LINEAR UNCLAMPED
// destinations (HW writes wave-uniform-base + lane*16 — R10's clamped dest
// raced and corrupted off_l):
//   batch1 = 3/thread, slots 0..1151 (covers ref section) — no clamp
//   batch2 = 5/thread, slots 1152..3071 (src clamped, dest into 48-slot pad)
// vmcnt(5)+barrier after issue => ref ready; Phase A overlaps batch2 flight;
// __syncthreads (vmcnt 0) drains before Phase B. LDS 51456 B -> 3 blocks/CU.
// ===========================================================================
struct CtxF {                    // fast path only (register diet)
    int l00, l01, l10, l11;      // pr*128 + (pr&7) packed
    float W00, W01, W10, W11;
    int inh;
};

__device__ __forceinline__ CtxF mkctx_fast(int t, int y, int x, int xb, int yb,
                                           float2 o2) {
    CtxF c;
    float py = (float)(y - 1 + t / 3) + o2.x;
    float pxs = (float)(x - 1 + t % 3) + o2.y;
    float fy = floorf(py), fx = floorf(pxs);
    int y0 = (int)fy, x0 = (int)fx;
    int y1 = y0 + 1, x1 = x0 + 1;
    float ay = py - fy, ax = pxs - fx;
    bool vy0 = (unsigned)y0 < (unsigned)Hd;
    bool vy1 = (unsigned)y1 < (unsigned)Hd;
    bool vx0 = (unsigned)x0 < (unsigned)Wd;
    bool vx1 = (unsigned)x1 < (unsigned)Wd;
    c.W00 = (vy0 && vx0) ? (1.f - ay) * (1.f - ax) : 0.f;
    c.W01 = (vy0 && vx1) ? (1.f - ay) * ax : 0.f;
    c.W10 = (vy1 && vx0) ? ay * (1.f - ax) : 0.f;
    c.W11 = (vy1 && vx1) ? ay * ax : 0.f;
    int y0c = min(max(y0, 0), Hd - 1), y1c = min(max(y1, 0), Hd - 1);
    int x0c = min(max(x0, 0), Wd - 1), x1c = min(max(x1, 0), Wd - 1);
    int iy0 = y0c - yb + 2, iy1 = y1c - yb + 2;      // halo row 0 = yb-2
    int ix0 = x0c - xb + 3, ix1 = x1c - xb + 3;
    c.inh = ((unsigned)iy0 < (unsigned)HR2) & ((unsigned)iy1 < (unsigned)HR2) &
            ((unsigned)ix0 < (unsigned)HC) & ((unsigned)ix1 < (unsigned)HC);
    int p00 = iy0 * HC + ix0, p01 = iy0 * HC + ix1;
    int p10 = iy1 * HC + ix0, p11 = iy1 * HC + ix1;
    c.l00 = p00 * 128 + (p00 & 7);
    c.l01 = p01 * 128 + (p01 & 7);
    c.l10 = p10 * 128 + (p10 & 7);
    c.l11 = p11 * 128 + (p11 & 7);
    return c;
}

__device__ __forceinline__ __half2 uh2(unsigned u) {
    return __builtin_bit_cast(__half2, u);
}

// Bilinear blend on packed f16 pairs + 4 MFMAs, for one (tap, kc-triple).
__device__ __forceinline__ void bilin_mfma(const s8v* rw,
        float W00, float W01, float W10, float W11,
        const s8v* __restrict__ Ap, int t, int kb, int L, f4v* acc) {
    __half2 w00 = __float2half2_rn(W00);
    __half2 w01 = __float2half2_rn(W01);
    __half2 w10 = __float2half2_rn(W10);
    __half2 w11 = __float2half2_rn(W11);
#pragma unroll
    for (int i = 0; i < 3; ++i) {
        int kc = kb + i;
        u4v u00 = __builtin_bit_cast(u4v, rw[0 * 3 + i]);
        u4v u01 = __builtin_bit_cast(u4v, rw[1 * 3 + i]);
        u4v u10 = __builtin_bit_cast(u4v, rw[2 * 3 + i]);
        u4v u11 = __builtin_bit_cast(u4v, rw[3 * 3 + i]);
        u4v bu;
#pragma unroll
        for (int p = 0; p < 4; ++p) {
            __half2 v = __hmul2(uh2(u00[p]), w00);
            v = __hfma2(uh2(u01[p]), w01, v);
            v = __hfma2(uh2(u10[p]), w10, v);
            v = __hfma2(uh2(u11[p]), w11, v);
            bu[p] = __builtin_bit_cast(unsigned, v);
        }
        h8v bfrag = __builtin_bit_cast(h8v, bu);
#pragma unroll
        for (int mt = 0; mt < 4; ++mt) {
            h8v a = __builtin_bit_cast(h8v, Ap[((t * 6 + kc) * 4 + mt) * 64 + L]);
            acc[mt] = __builtin_amdgcn_mfma_f32_16x16x32_f16(a, bfrag, acc[mt], 0, 0, 0);
        }
    }
}

__global__ __launch_bounds__(384, 4) void fused_mfma(
        const __half* __restrict__ packed,
        const __half* __restrict__ wtb2,
        const float* __restrict__ ob,
        const __half* __restrict__ wtb,
        const float* __restrict__ db,
        float* __restrict__ out) {
    __shared__ __align__(16) char smem[HALO_B + 2 * 16 * 18 * 4];   // 51456 B
    float (*off_l)[18] = (float(*)[18])(smem + HALO_B);   // [32][18], after pad
    float* redB = (float*)smem;                           // aliases halo

    int tid = threadIdx.x;
    int L = tid & 63;
    int wv = tid >> 6;                        // 0..5
    int g  = wv / 3;                          // row group 0..1
    int kv = wv - g * 3;                      // split-K 0..2 (Phase B)
    int px = L & 15;
    int lg = L >> 4;
    int blk = blockIdx.x;
    int region = (blk & 7) * 144 + (blk >> 3);        // 1152 blocks, XCD swizzle
    int b = region / 288;
    int rt = region - b * 288;
    int yt = rt / 6;
    int xt = rt - yt * 6;
    int yb = yt * 2, xb = xt * 16;            // tile: rows yb..yb+1, cols xb..+15
    int y = yb + g, x = xb + px;
    int pb = y * Wd + xb;                     // this group's output row base
    int tbase = kv * 3;

    const char* pkb = (const char*)packed + (size_t)b * HW * (C3 * 2);
    const char* hb = (const char*)smem;

    // ------- stage halo: batch1 (slots 0..1151, covers ref) then batch2 ----
    // dest ALWAYS linear-unclamped (HW: wave-uniform base + lane*16);
    // only the SOURCE index is clamped. Each wave issues exactly 8 DMAs.
    {
        auto stage_one = [&](int Sdst, int Ssrc) {
            int sec = (Ssrc >= 2 * SECT_SL) ? 2 : (Ssrc >= SECT_SL ? 1 : 0);
            int rem = Ssrc - sec * SECT_SL;
            int pr = rem >> 3, sl = rem & 7;
            int chb = sec * 8 + (sl ^ (pr & 7));      // inverse swizzle on src
            int iy = pr / HC, ix = pr - iy * HC;
            int gy = min(max(yb - 2 + iy, 0), Hd - 1);
            int gx = min(max(xb - 3 + ix, 0), Wd - 1);
            gload_lds16(pkb + ((size_t)(gy * Wd + gx)) * 384 + chb * 16,
                        (char*)smem + (size_t)Sdst * 16);
        };
        __builtin_amdgcn_sched_barrier(0);
#pragma unroll
        for (int r = 0; r < 3; ++r) {                 // batch1: slots 0..1151
            int S = tid + r * 384;
            stage_one(S, S);
        }
        __builtin_amdgcn_sched_barrier(0);            // pin batch order
#pragma unroll
        for (int r = 0; r < 5; ++r) {                 // batch2: 1152..3071
            int S = 1152 + tid + r * 384;
            stage_one(S, min(S, SELEM - 1));          // pad slots dup src 3023
        }
    }
    __builtin_amdgcn_sched_barrier(0);
    asm volatile("s_waitcnt vmcnt(5)" ::: "memory");  // my batch1 drained
    __builtin_amdgcn_s_barrier();                     // everyone's batch1 done
    __builtin_amdgcn_sched_barrier(0);

    // ------- Phase A: offset conv — ONE wave per row-group, ref section ----
    // (runs while batch2 DMAs are still in flight)
    if (kv == 0) {
        const s8v* Ap = (const s8v*)wtb2;
        f4v acc0 = {0.f, 0.f, 0.f, 0.f};
        f4v acc1 = {0.f, 0.f, 0.f, 0.f};
#pragma unroll
        for (int t = 0; t < 9; ++t) {
            int ty = t / 3, tx = t - ty * 3;
            int yy = y - 1 + ty, xx = x - 1 + tx;
            bool val = (unsigned)yy < (unsigned)Hd && (unsigned)xx < (unsigned)Wd;
            short m = val ? (short)-1 : (short)0;
            int pr = (g + 1 + ty) * HC + (px + 2 + tx);
            int pbase = pr * 128;
            int key = pr & 7;
#pragma unroll
            for (int kc = 0; kc < 2; ++kc) {
                int chb = kc * 4 + lg;                // sec 0
                s8v braw = *(const s8v*)(hb + pbase + ((chb ^ key) << 4)) & m;
                h8v bfrag = __builtin_bit_cast(h8v, braw);
                h8v a0 = __builtin_bit_cast(h8v, Ap[((t * 2 + kc) * 2 + 0) * 64 + L]);
                h8v a1 = __builtin_bit_cast(h8v, Ap[((t * 2 + kc) * 2 + 1) * 64 + L]);
                acc0 = __builtin_amdgcn_mfma_f32_16x16x32_f16(a0, bfrag, acc0, 0, 0, 0);
                acc1 = __builtin_amdgcn_mfma_f32_16x16x32_f16(a1, bfrag, acc1, 0, 0, 0);
            }
        }
#pragma unroll
        for (int r = 0; r < 4; ++r) {
            int v = lg * 4 + r;
            off_l[g * 16 + px][v] = acc0[r] + ob[v];
        }
        if (lg == 0) {
#pragma unroll
            for (int r = 0; r < 2; ++r)
                off_l[g * 16 + px][16 + r] = acc1[r] + ob[16 + r];
        }
    }
    __syncthreads();          // drains batch2 (vmcnt 0) + publishes off_l

    // ---------------- Phase B: deform conv ----------------
    const s8v* Ap = (const s8v*)wtb;

    float2 o2a[3];
    CtxF ctx[3];
    int ok = 1;
#pragma unroll
    for (int tt = 0; tt < 3; ++tt) {
        int t = tbase + tt;
        o2a[tt].x = off_l[g * 16 + px][2 * t];
        o2a[tt].y = off_l[g * 16 + px][2 * t + 1];
        ctx[tt] = mkctx_fast(t, y, x, xb, yb, o2a[tt]);
        ok &= ctx[tt].inh;
    }

    f4v acc[4];
    acc[0] = acc[1] = acc[2] = acc[3] = (f4v){0.f, 0.f, 0.f, 0.f};

    __builtin_amdgcn_s_setprio(1);
    if (__all(ok)) {
        // fast path: bilinear gathers from section-major swizzled LDS halo
#pragma unroll
        for (int h = 0; h < 6; ++h) {             // 3 taps x 2 halves
            int tt = h >> 1;
            int t = tbase + tt;
            int kb = (h & 1) * 3;
            const CtxF cc = ctx[tt];
            int b00 = cc.l00 & ~127, k00 = cc.l00 & 7;
            int b01 = cc.l01 & ~127, k01 = cc.l01 & 7;
            int b10 = cc.l10 & ~127, k10 = cc.l10 & 7;
            int b11 = cc.l11 & ~127, k11 = cc.l11 & 7;
            s8v rw[12];
#pragma unroll
            for (int i = 0; i < 3; ++i) {
                int secoff = ((kb + i) >> 1) * SECT_B;        // compile-time
                int chb3 = ((kb + i) & 1) * 4 + lg;           // cb & 7
                rw[0 * 3 + i] = *(const s8v*)(hb + secoff + b00 + ((chb3 ^ k00) << 4));
                rw[1 * 3 + i] = *(const s8v*)(hb + secoff + b01 + ((chb3 ^ k01) << 4));
                rw[2 * 3 + i] = *(const s8v*)(hb + secoff + b10 + ((chb3 ^ k10) << 4));
                rw[3 * 3 + i] = *(const s8v*)(hb + secoff + b11 + ((chb3 ^ k11) << 4));
            }
            bilin_mfma(rw, cc.W00, cc.W01, cc.W10, cc.W11, Ap, t, kb, L, acc);
        }
    } else {
        // fallback: global gathers; recompute addresses in-branch (cold)
#pragma unroll
        for (int tt = 0; tt < 3; ++tt) {
            int t = tbase + tt;
            float py = (float)(y - 1 + t / 3) + o2a[tt].x;
            float pxs = (float)(x - 1 + t % 3) + o2a[tt].y;
            float fy = floorf(py), fx = floorf(pxs);
            int y0 = (int)fy, x0 = (int)fx;
            int y0c = min(max(y0, 0), Hd - 1), y1c = min(max(y0 + 1, 0), Hd - 1);
            int x0c = min(max(x0, 0), Wd - 1), x1c = min(max(x0 + 1, 0), Wd - 1);
            int o00 = (y0c * Wd + x0c) * 384, o01 = (y0c * Wd + x1c) * 384;
            int o10 = (y1c * Wd + x0c) * 384, o11 = (y1c * Wd + x1c) * 384;
#pragma unroll
            for (int half = 0; half < 2; ++half) {
                int kb = half * 3;
                s8v rw[12];
#pragma unroll
                for (int i = 0; i < 3; ++i) {
                    int co = ((kb + i) * 4 + lg) * 16;
                    rw[0 * 3 + i] = *(const s8v*)(pkb + o00 + co);
                    rw[1 * 3 + i] = *(const s8v*)(pkb + o01 + co);
                    rw[2 * 3 + i] = *(const s8v*)(pkb + o10 + co);
                    rw[3 * 3 + i] = *(const s8v*)(pkb + o11 + co);
                }
                bilin_mfma(rw, ctx[tt].W00, ctx[tt].W01, ctx[tt].W10, ctx[tt].W11,
                           Ap, t, kb, L, acc);
            }
        }
    }
    __builtin_amdgcn_s_setprio(0);

    // -------- reduction: redB aliases halo (all halo reads done) -----------
    __syncthreads();
    if (kv != 0) {
        float* r = redB + ((g * 2 + kv - 1) * 64 + L) * 17;
#pragma unroll
        for (int mt = 0; mt < 4; ++mt)
#pragma unroll
            for (int q = 0; q < 4; ++q)
                r[mt * 4 + q] = acc[mt][q];
    }
    __syncthreads();
    if (kv == 0) {
        const float* r0 = redB + ((g * 2 + 0) * 64 + L) * 17;
        const float* r1 = redB + ((g * 2 + 1) * 64 + L) * 17;
#pragma unroll
        for (int mt = 0; mt < 4; ++mt) {
#pragma unroll
            for (int q = 0; q < 4; ++q) {
                int o = mt * 16 + lg * 4 + q;
                float v = acc[mt][q] + r0[mt * 4 + q] + r1[mt * 4 + q] + db[o];
                out[((size_t)(b * On + o)) * HW + pb + px] = fmaxf(v, 0.f);
            }
        }
    }
}

// ---------------------------------------------------------------------------
extern "C" void kernel_launch(void* const* d_in, const int* in_sizes, int n_in,
                              void* d_out, int out_size, void* d_ws, size_t ws_size,
                              hipStream_t stream) {
    const float* ref  = (const float*)d_in[0];
    const float* dist = (const float*)d_in[1];
    const float* ow   = (const float*)d_in[2];
    const float* ob   = (const float*)d_in[3];
    const float* dw   = (const float*)d_in[4];
    const float* db   = (const float*)d_in[5];

    float* out = (float*)d_out;               // [feat | diff], each NFEAT f32

    // ws: wtb f16 | wtb2 f16 | packed f16 [NPIX][192]
    __half* ws_wtb  = (__half*)d_ws;
    __half* ws_wtb2 = ws_wtb + NWTB;
    __half* ws_pk   = ws_wtb2 + NWTB2;

    int wts_blocks = (NWTB + NWTB2 + 255) / 256;      // 504
    repack_wts_kernel<<<NRB3 + wts_blocks, 256, 0, stream>>>(
        ref, dist, (unsigned int*)ws_pk, out + NFEAT, dw, ow, ws_wtb, ws_wtb2);
    fused_mfma<<<NFBLK, 384, 0, stream>>>(
        ws_pk, ws_wtb2, ob, ws_wtb, db, out);
}